// Round 2
// baseline (1859.220 us; speedup 1.0000x reference)
//
#include <hip/hip_runtime.h>

// Problem constants (fixed by reference: x is (2, 4, 128, 128, 128) fp32)
#define NBATCH 2
#define NDIM   128
#define NP     (128 * 128 * 128)        // particles per batch = mesh cells (2^21)
#define DIS_NORM 3.072f                  // 6 * 512 / 1000
#define NXCD   8                         // MI355X XCD count [measured m09]

// ws layout: [0..8) fp32 mean-sums (only 6 used), [8 ..) 8 per-XCD partial meshes
#define SUMS_FLOATS 8
#define PART_FLOATS ((size_t)NXCD * NBATCH * NP)
#define WS_NEEDED_BYTES ((SUMS_FLOATS + PART_FLOATS) * sizeof(float))

__device__ __forceinline__ int get_xcc_id() {
    int x;
    asm volatile("s_getreg_b32 %0, hwreg(HW_REG_XCC_ID)" : "=s"(x));
    return x & (NXCD - 1);
}

// ---------------------------------------------------------------------------
// Kernel 1: per-(batch,channel) sums of the 3 displacement channels.
// ---------------------------------------------------------------------------
__global__ __launch_bounds__(256) void sum_disp_kernel(const float* __restrict__ x,
                                                       float* __restrict__ sums) {
    const int plane = blockIdx.y;            // 0..5
    const int n = plane / 3, c = plane % 3;
    const float4* xp = (const float4*)(x + ((size_t)n * 4 + c) * NP);
    const int nvec = NP / 4;

    float s = 0.0f;
    for (int i = blockIdx.x * blockDim.x + threadIdx.x; i < nvec;
         i += gridDim.x * blockDim.x) {
        float4 v = xp[i];
        s += (v.x + v.y) + (v.z + v.w);
    }
    #pragma unroll
    for (int off = 32; off > 0; off >>= 1) s += __shfl_down(s, off, 64);
    if ((threadIdx.x & 63) == 0) atomicAdd(&sums[plane], s);
}

// ---------------------------------------------------------------------------
// Shared per-particle deposit logic
// ---------------------------------------------------------------------------
template <bool USE_PART>
__device__ __forceinline__ void deposit(const float* __restrict__ x,
                                        const float* __restrict__ sums,
                                        float* __restrict__ mesh,  // batch-n mesh (partial or out)
                                        int n, int p) {
    const float inv_np = 1.0f / (float)NP;
    const float m0 = sums[n * 3 + 0] * inv_np;
    const float m1 = sums[n * 3 + 1] * inv_np;
    const float m2 = sums[n * 3 + 2] * inv_np;

    const size_t base = (size_t)n * 4 * NP;
    const float d0 = x[base + 0 * (size_t)NP + p];
    const float d1 = x[base + 1 * (size_t)NP + p];
    const float d2 = x[base + 2 * (size_t)NP + p];
    const float v  = x[base + 3 * (size_t)NP + p];

    const int w = p & 127;
    const int h = (p >> 7) & 127;
    const int d = p >> 14;

    const float pd = (d0 - m0) * DIS_NORM + ((float)d + 0.5f);
    const float ph = (d1 - m1) * DIS_NORM + ((float)h + 0.5f);
    const float pw = (d2 - m2) * DIS_NORM + ((float)w + 0.5f);

    const float fd = floorf(pd), fh = floorf(ph), fw = floorf(pw);
    const int id = (int)fd, ih = (int)fh, iw = (int)fw;
    const float rd = pd - fd, rh = ph - fh, rw = pw - fw;

    const float wd[2]  = {1.0f - rd, rd};
    const float wh[2]  = {1.0f - rh, rh};
    const float wwt[2] = {1.0f - rw, rw};

    #pragma unroll
    for (int dd = 0; dd < 2; ++dd) {
        const int td = id + dd;
        if ((unsigned)td >= (unsigned)NDIM) continue;
        #pragma unroll
        for (int hh = 0; hh < 2; ++hh) {
            const int th = ih + hh;
            if ((unsigned)th >= (unsigned)NDIM) continue;
            const float wdh = v * wd[dd] * wh[hh];
            const int rowbase = (td * NDIM + th) * NDIM;
            #pragma unroll
            for (int wi = 0; wi < 2; ++wi) {
                const int tw = iw + wi;
                if ((unsigned)tw >= (unsigned)NDIM) continue;
                if (USE_PART) {
                    // XCD-local L2 atomic: all blocks that can touch this
                    // partial share one L2 (partial is indexed by XCC_ID).
                    __hip_atomic_fetch_add(mesh + rowbase + tw, wdh * wwt[wi],
                                           __ATOMIC_RELAXED,
                                           __HIP_MEMORY_SCOPE_WORKGROUP);
                } else {
                    atomicAdd(mesh + rowbase + tw, wdh * wwt[wi]);
                }
            }
        }
    }
}

// ---------------------------------------------------------------------------
// Kernel 2a: CIC scatter into per-XCD partial meshes (L2-local atomics).
// 1D grid over both batches so batch 0 finishes dispatch before batch 1
// (halves the live L2 working set).
// ---------------------------------------------------------------------------
__global__ __launch_bounds__(256) void scatter_part_kernel(const float* __restrict__ x,
                                                           const float* __restrict__ sums,
                                                           float* __restrict__ part) {
    const int lin = blockIdx.x * 256 + threadIdx.x;  // 0 .. 2*NP-1
    const int n = lin >> 21;                          // NP = 2^21
    const int p = lin & (NP - 1);
    const int xcc = get_xcc_id();
    float* mesh = part + ((size_t)(xcc * NBATCH + n)) * NP;
    deposit<true>(x, sums, mesh, n, p);
}

// Kernel 2b: fallback — direct device-scope atomics into d_out.
__global__ __launch_bounds__(256) void scatter_direct_kernel(const float* __restrict__ x,
                                                             const float* __restrict__ sums,
                                                             float* __restrict__ out) {
    const int lin = blockIdx.x * 256 + threadIdx.x;
    const int n = lin >> 21;
    const int p = lin & (NP - 1);
    deposit<false>(x, sums, out + (size_t)n * NP, n, p);
}

// ---------------------------------------------------------------------------
// Kernel 3: reduce 8 partials -> out. float4 grid-stride free.
// ---------------------------------------------------------------------------
__global__ __launch_bounds__(256) void reduce_part_kernel(const float* __restrict__ part,
                                                          float* __restrict__ out) {
    const size_t i = (size_t)blockIdx.x * 256 + threadIdx.x;  // over NBATCH*NP/4 = 2^20
    const int n = (int)(i >> 19);                             // NP/4 = 2^19
    const size_t off = i & ((size_t)(NP / 4) - 1);

    float4 acc = make_float4(0.f, 0.f, 0.f, 0.f);
    #pragma unroll
    for (int xc = 0; xc < NXCD; ++xc) {
        const float4 v =
            ((const float4*)(part + ((size_t)(xc * NBATCH + n)) * NP))[off];
        acc.x += v.x; acc.y += v.y; acc.z += v.z; acc.w += v.w;
    }
    ((float4*)out)[i] = acc;
}

extern "C" void kernel_launch(void* const* d_in, const int* in_sizes, int n_in,
                              void* d_out, int out_size, void* d_ws, size_t ws_size,
                              hipStream_t stream) {
    const float* x = (const float*)d_in[0];
    float* out = (float*)d_out;
    float* sums = (float*)d_ws;
    float* part = sums + SUMS_FLOATS;

    dim3 sgrid(128, 6);

    if (ws_size >= WS_NEEDED_BYTES) {
        // Zero sums + partial meshes (harness poisons ws with 0xAA)
        hipMemsetAsync(d_ws, 0, WS_NEEDED_BYTES, stream);
        sum_disp_kernel<<<sgrid, 256, 0, stream>>>(x, sums);
        scatter_part_kernel<<<dim3(NBATCH * NP / 256), 256, 0, stream>>>(x, sums, part);
        reduce_part_kernel<<<dim3(NBATCH * NP / 4 / 256), 256, 0, stream>>>(part, out);
    } else {
        // Fallback: R1 path (device-scope atomics straight into out)
        hipMemsetAsync(d_ws, 0, SUMS_FLOATS * sizeof(float), stream);
        hipMemsetAsync(out, 0, (size_t)out_size * sizeof(float), stream);
        sum_disp_kernel<<<sgrid, 256, 0, stream>>>(x, sums);
        scatter_direct_kernel<<<dim3(NBATCH * NP / 256), 256, 0, stream>>>(x, sums, out);
    }
}

// Round 3
// 340.534 us; speedup vs baseline: 5.4597x; 5.4597x over previous
//
#include <hip/hip_runtime.h>

// Problem constants (fixed by reference: x is (2, 4, 128, 128, 128) fp32)
#define NBATCH 2
#define NDIM   128
#define NP     (128 * 128 * 128)        // particles per batch = mesh cells (2^21)
#define DIS_NORM 3.072f                  // 6 * 512 / 1000

// Tiling: 16^3 origin tiles, LDS window with halo LO=4 below, HI=5 above.
// Window = 25^3 floats = 61.04 KB -> 2 blocks/CU. Deposits outside window
// (P ~ 5% of particles for sigma=3.07 displacements) spill via global atomics.
#define TS  16
#define LO  4
#define HI  5
#define WIN (TS + LO + HI)               // 25
#define WINF (WIN * WIN * WIN)           // 15625 floats
#define TPB 8                            // tiles per axis (128/16)
#define NTILE (TPB * TPB * TPB)          // 512 tiles per batch
#define SLOT 15632                       // padded window stride in scratch (16-mult)

// ws layout (floats): [0..8) mean sums, [8..8+2NP) spill mesh, [WINS_OFF..) windows
#define SUMS_OFF 0
#define SPILL_OFF 8
#define WINS_OFF (SPILL_OFF + NBATCH * NP + 8)   // 4194320, 16-aligned
#define WS_FLOATS ((size_t)WINS_OFF + (size_t)NBATCH * NTILE * SLOT)
#define WS_NEEDED_BYTES (WS_FLOATS * sizeof(float))

// ---------------------------------------------------------------------------
// Kernel 1: per-(batch,channel) sums of the 3 displacement channels.
// ---------------------------------------------------------------------------
__global__ __launch_bounds__(256) void sum_disp_kernel(const float* __restrict__ x,
                                                       float* __restrict__ sums) {
    const int plane = blockIdx.y;            // 0..5
    const int n = plane / 3, c = plane % 3;
    const float4* xp = (const float4*)(x + ((size_t)n * 4 + c) * NP);
    const int nvec = NP / 4;

    float s = 0.0f;
    for (int i = blockIdx.x * blockDim.x + threadIdx.x; i < nvec;
         i += gridDim.x * blockDim.x) {
        float4 v = xp[i];
        s += (v.x + v.y) + (v.z + v.w);
    }
    #pragma unroll
    for (int off = 32; off > 0; off >>= 1) s += __shfl_down(s, off, 64);
    if ((threadIdx.x & 63) == 0) atomicAdd(&sums[plane], s);
}

// ---------------------------------------------------------------------------
// Kernel 2: tiled CIC scatter. Block = one 16^3 origin tile; LDS atomics into
// a 25^3 halo window; rare out-of-window particles spill to a global spill
// mesh; window flushed to a private scratch slot with plain stores.
// ---------------------------------------------------------------------------
__global__ __launch_bounds__(512) void scatter_tile_kernel(const float* __restrict__ x,
                                                           const float* __restrict__ sums,
                                                           float* __restrict__ wins,
                                                           float* __restrict__ spill) {
    const int blk = blockIdx.x;              // 0 .. 2*NTILE-1
    const int n = blk >> 9;                  // NTILE = 512
    const int t = blk & (NTILE - 1);
    const int tx = t & 7, ty = (t >> 3) & 7, tz = t >> 6;

    extern __shared__ float win[];
    for (int i = threadIdx.x; i < WINF; i += 512) win[i] = 0.0f;
    __syncthreads();

    const float inv_np = 1.0f / (float)NP;
    const float m0 = sums[n * 3 + 0] * inv_np;
    const float m1 = sums[n * 3 + 1] * inv_np;
    const float m2 = sums[n * 3 + 2] * inv_np;

    // Thread handles 8 consecutive particles of the 4096-particle tile.
    const int i0 = threadIdx.x * 8;
    const int lw0 = i0 & 15;                 // 0 or 8
    const int lh  = (i0 >> 4) & 15;
    const int ld  = i0 >> 8;
    const int gd = tz * TS + ld, gh = ty * TS + lh, gw0 = tx * TS + lw0;
    const size_t prow = ((size_t)gd * NDIM + gh) * NDIM + gw0;  // mult of 4

    const float4* x4 = (const float4*)(x + (size_t)n * 4 * NP);
    const size_t q = prow >> 2;
    const size_t s4 = NP / 4;
    float4 a0 = x4[0 * s4 + q], a1 = x4[0 * s4 + q + 1];
    float4 b0 = x4[1 * s4 + q], b1 = x4[1 * s4 + q + 1];
    float4 c0 = x4[2 * s4 + q], c1 = x4[2 * s4 + q + 1];
    float4 e0 = x4[3 * s4 + q], e1 = x4[3 * s4 + q + 1];
    const float D0[8] = {a0.x, a0.y, a0.z, a0.w, a1.x, a1.y, a1.z, a1.w};
    const float D1[8] = {b0.x, b0.y, b0.z, b0.w, b1.x, b1.y, b1.z, b1.w};
    const float D2[8] = {c0.x, c0.y, c0.z, c0.w, c1.x, c1.y, c1.z, c1.w};
    const float VV[8] = {e0.x, e0.y, e0.z, e0.w, e1.x, e1.y, e1.z, e1.w};

    // window origin in mesh coords
    const int od = tz * TS - LO, oh = ty * TS - LO, ow = tx * TS - LO;
    float* sp = spill + (size_t)n * NP;

    #pragma unroll
    for (int k = 0; k < 8; ++k) {
        const float pd = (D0[k] - m0) * DIS_NORM + (float)gd + 0.5f;
        const float ph = (D1[k] - m1) * DIS_NORM + (float)gh + 0.5f;
        const float pw = (D2[k] - m2) * DIS_NORM + (float)(gw0 + k) + 0.5f;
        const float v = VV[k];

        const float fd = floorf(pd), fh = floorf(ph), fw = floorf(pw);
        const int id = (int)fd, ih = (int)fh, iw = (int)fw;
        const float rd = pd - fd, rh = ph - fh, rw = pw - fw;

        const int wd = id - od, wh = ih - oh, ww = iw - ow;
        if ((unsigned)wd <= WIN - 2 && (unsigned)wh <= WIN - 2 &&
            (unsigned)ww <= WIN - 2) {
            // all 8 deposits inside the LDS window
            const int b = (wd * WIN + wh) * WIN + ww;
            const float w0 = v * (1.0f - rd), w1 = v * rd;
            const float h0 = 1.0f - rh, h1 = rh;
            const float q0 = 1.0f - rw, q1 = rw;
            atomicAdd(&win[b],                     w0 * h0 * q0);
            atomicAdd(&win[b + 1],                 w0 * h0 * q1);
            atomicAdd(&win[b + WIN],               w0 * h1 * q0);
            atomicAdd(&win[b + WIN + 1],           w0 * h1 * q1);
            atomicAdd(&win[b + WIN * WIN],         w1 * h0 * q0);
            atomicAdd(&win[b + WIN * WIN + 1],     w1 * h0 * q1);
            atomicAdd(&win[b + WIN * WIN + WIN],   w1 * h1 * q0);
            atomicAdd(&win[b + WIN * WIN + WIN + 1], w1 * h1 * q1);
        } else {
            // spill: global atomics with bounds mask (matches reference mask)
            const float wd2[2]  = {1.0f - rd, rd};
            const float wh2[2]  = {1.0f - rh, rh};
            const float ww2[2]  = {1.0f - rw, rw};
            #pragma unroll
            for (int dd = 0; dd < 2; ++dd) {
                const int td = id + dd;
                if ((unsigned)td >= (unsigned)NDIM) continue;
                #pragma unroll
                for (int hh = 0; hh < 2; ++hh) {
                    const int th = ih + hh;
                    if ((unsigned)th >= (unsigned)NDIM) continue;
                    const float vdh = v * wd2[dd] * wh2[hh];
                    const int rowbase = (td * NDIM + th) * NDIM;
                    #pragma unroll
                    for (int wi = 0; wi < 2; ++wi) {
                        const int tw = iw + wi;
                        if ((unsigned)tw >= (unsigned)NDIM) continue;
                        atomicAdd(sp + rowbase + tw, vdh * ww2[wi]);
                    }
                }
            }
        }
    }

    __syncthreads();
    // flush window to private scratch slot (plain coalesced stores)
    float* dst = wins + (size_t)blk * SLOT;
    for (int i = threadIdx.x; i < WINF; i += 512) dst[i] = win[i];
}

// ---------------------------------------------------------------------------
// Kernel 3: gather. Each output cell sums the <=8 scratch windows covering it
// plus the spill mesh. Each window value is consumed by exactly one cell.
// ---------------------------------------------------------------------------
__device__ __forceinline__ int axis_tiles(int c, int* t, int* l) {
    const int r = c & (TS - 1), t0 = c >> 4;
    int cnt = 0;
    t[cnt] = t0; l[cnt] = r + LO; cnt++;
    if (r < HI && t0 > 0)            { t[cnt] = t0 - 1; l[cnt] = r + TS + LO; cnt++; }
    if (r >= TS - LO && t0 < TPB - 1){ t[cnt] = t0 + 1; l[cnt] = r - (TS - LO); cnt++; }
    return cnt;
}

__global__ __launch_bounds__(256) void gather_kernel(const float* __restrict__ wins,
                                                     const float* __restrict__ spill,
                                                     float* __restrict__ out) {
    const size_t i = (size_t)blockIdx.x * 256 + threadIdx.x;  // 0..2NP
    const int n = (int)(i >> 21);
    const int p = (int)(i & (NP - 1));
    const int w = p & 127, h = (p >> 7) & 127, d = p >> 14;

    float acc = spill[i];

    int tzv[2], lzv[2], tyv[2], lyv[2], txv[2], lxv[2];
    const int nz = axis_tiles(d, tzv, lzv);
    const int ny = axis_tiles(h, tyv, lyv);
    const int nx = axis_tiles(w, txv, lxv);

    for (int a = 0; a < nz; ++a) {
        for (int b = 0; b < ny; ++b) {
            const int tbase = n * NTILE + tzv[a] * 64 + tyv[b] * 8;
            const int lbase = (lzv[a] * WIN + lyv[b]) * WIN;
            for (int c = 0; c < nx; ++c) {
                acc += wins[(size_t)(tbase + txv[c]) * SLOT + lbase + lxv[c]];
            }
        }
    }
    out[i] = acc;
}

// ---------------------------------------------------------------------------
// Fallback (small ws): direct device-scope atomic scatter (R1 path)
// ---------------------------------------------------------------------------
__global__ __launch_bounds__(256) void scatter_direct_kernel(const float* __restrict__ x,
                                                             const float* __restrict__ sums,
                                                             float* __restrict__ out) {
    const int lin = blockIdx.x * 256 + threadIdx.x;
    const int n = lin >> 21;
    const int p = lin & (NP - 1);

    const float inv_np = 1.0f / (float)NP;
    const float m0 = sums[n * 3 + 0] * inv_np;
    const float m1 = sums[n * 3 + 1] * inv_np;
    const float m2 = sums[n * 3 + 2] * inv_np;

    const size_t base = (size_t)n * 4 * NP;
    const float d0 = x[base + 0 * (size_t)NP + p];
    const float d1 = x[base + 1 * (size_t)NP + p];
    const float d2 = x[base + 2 * (size_t)NP + p];
    const float v  = x[base + 3 * (size_t)NP + p];

    const int w = p & 127, h = (p >> 7) & 127, d = p >> 14;
    const float pd = (d0 - m0) * DIS_NORM + (float)d + 0.5f;
    const float ph = (d1 - m1) * DIS_NORM + (float)h + 0.5f;
    const float pw = (d2 - m2) * DIS_NORM + (float)w + 0.5f;
    const float fd = floorf(pd), fh = floorf(ph), fw = floorf(pw);
    const int id = (int)fd, ih = (int)fh, iw = (int)fw;
    const float rd = pd - fd, rh = ph - fh, rw = pw - fw;
    const float wd[2] = {1.0f - rd, rd}, wh[2] = {1.0f - rh, rh}, ww[2] = {1.0f - rw, rw};
    float* o = out + (size_t)n * NP;
    #pragma unroll
    for (int dd = 0; dd < 2; ++dd) {
        const int td = id + dd;
        if ((unsigned)td >= (unsigned)NDIM) continue;
        #pragma unroll
        for (int hh = 0; hh < 2; ++hh) {
            const int th = ih + hh;
            if ((unsigned)th >= (unsigned)NDIM) continue;
            const float vdh = v * wd[dd] * wh[hh];
            const int rowbase = (td * NDIM + th) * NDIM;
            #pragma unroll
            for (int wi = 0; wi < 2; ++wi) {
                const int tw = iw + wi;
                if ((unsigned)tw >= (unsigned)NDIM) continue;
                atomicAdd(o + rowbase + tw, vdh * ww[wi]);
            }
        }
    }
}

extern "C" void kernel_launch(void* const* d_in, const int* in_sizes, int n_in,
                              void* d_out, int out_size, void* d_ws, size_t ws_size,
                              hipStream_t stream) {
    const float* x = (const float*)d_in[0];
    float* out = (float*)d_out;
    float* ws = (float*)d_ws;
    float* sums  = ws + SUMS_OFF;
    float* spill = ws + SPILL_OFF;
    float* wins  = ws + WINS_OFF;

    dim3 sgrid(128, 6);

    if (ws_size >= WS_NEEDED_BYTES) {
        // zero sums + spill mesh only (windows are fully overwritten)
        hipMemsetAsync(d_ws, 0, (size_t)WINS_OFF * sizeof(float), stream);
        sum_disp_kernel<<<sgrid, 256, 0, stream>>>(x, sums);
        scatter_tile_kernel<<<dim3(NBATCH * NTILE), 512, WINF * sizeof(float), stream>>>(
            x, sums, wins, spill);
        gather_kernel<<<dim3(NBATCH * NP / 256), 256, 0, stream>>>(wins, spill, out);
    } else {
        hipMemsetAsync(d_ws, 0, 8 * sizeof(float), stream);
        hipMemsetAsync(out, 0, (size_t)out_size * sizeof(float), stream);
        sum_disp_kernel<<<sgrid, 256, 0, stream>>>(x, sums);
        scatter_direct_kernel<<<dim3(NBATCH * NP / 256), 256, 0, stream>>>(x, sums, out);
    }
}